// Round 6
// baseline (396.282 us; speedup 1.0000x reference)
//
#include <hip/hip_runtime.h>
#include <stdint.h>

typedef __bf16 bf16;
typedef __bf16 bf16x4 __attribute__((ext_vector_type(4)));
typedef __bf16 bf16x8 __attribute__((ext_vector_type(8)));
typedef float  fx4    __attribute__((ext_vector_type(4)));

#define MFMA16(a, b, c) __builtin_amdgcn_mfma_f32_16x16x32_bf16((a), (b), (c), 0, 0, 0)

// B=4, N=2048, E=768, H=8, D=96; M = B*N = 8192. User tensors fp32, out fp32.

// ---------------------------------------------------------------------------
// Barrier WITHOUT the vmem drain (lgkmcnt(0) only). Keeps global_load_lds
// DMA in flight across barriers. 0xC07F = vmcnt 63 (nowait), exp 7, lgkm 0.
// ---------------------------------------------------------------------------
__device__ __forceinline__ void barrier_nodrain() {
  __asm__ __volatile__("" ::: "memory");
  __builtin_amdgcn_s_waitcnt(0xC07F);
  __builtin_amdgcn_s_barrier();
  __asm__ __volatile__("" ::: "memory");
}

// Counted vmem wait: vmcnt(6) — wait oldest loads, allow 6 newest in flight.
__device__ __forceinline__ void wait_vm6() {
  __asm__ __volatile__("" ::: "memory");
  __builtin_amdgcn_s_waitcnt(0x0F76);
  __asm__ __volatile__("" ::: "memory");
}
// lgkmcnt(0) only (LDS reads retired; region safe to overwrite).
__device__ __forceinline__ void wait_lgkm0() {
  __asm__ __volatile__("" ::: "memory");
  __builtin_amdgcn_s_waitcnt(0xC07F);
  __asm__ __volatile__("" ::: "memory");
}

// DMA 16 B/lane global -> LDS (dest = wave-uniform base + lane*16, m104).
__device__ __forceinline__ void gload_lds16(const void* g, void* l) {
  __builtin_amdgcn_global_load_lds(
      (const __attribute__((address_space(1))) void*)g,
      (__attribute__((address_space(3))) void*)l, 16, 0, 0);
}

// ---------------------------------------------------------------------------
// x (fp32) -> bf16, 4 elems/thread.
// ---------------------------------------------------------------------------
__global__ __launch_bounds__(256)
void cvt_x_kernel(const float* __restrict__ x, bf16* __restrict__ xb) {
  const int i = (blockIdx.x * 256 + threadIdx.x) * 4;
  float4 v = *(const float4*)&x[i];
  bf16x4 o;
  o[0] = (bf16)v.x; o[1] = (bf16)v.y; o[2] = (bf16)v.z; o[3] = (bf16)v.w;
  *(bf16x4*)&xb[i] = o;
}

// ---------------------------------------------------------------------------
// Fused QKV GEMM. blockIdx.x: 0-5 Q, 6-11 K, 12-17 V. Tile 128x128, BK=32.
// R16 staging overhaul (m93->m97 ladder step):
//  - A tile staged via global_load_lds DMA (zero-VGPR staging). The c->
//    (row,kc) map is wave-linear: lane l of wave w covers LDS bytes
//    w*1024 + l*16, so dest = wave-uniform base + lane*16 (m104 constraint).
//  - B LDS tile ELIMINATED: a B-frag is 8 contiguous k of one W row =
//    32 contiguous global bytes (fp32). B rows have only 2-way block reuse;
//    W is 2.4 MB (L2-resident). Each wave loads its own float4 pairs and
//    converts at use — kills 16 scalar loads + 16 cvt + 2 ds_write/thread
//    of staging per K-step. LDS 16->8 KB => >=3 blocks/CU.
// K/V outputs in attention-staging tile layout (R15, unchanged):
//   K: [b][h][kt][u=d/8][k32][d%8]   V: [b][h][kt][ku=k/8][d96][k%8]
// ---------------------------------------------------------------------------
__global__ __launch_bounds__(256)
void gemm_qkv(const bf16* __restrict__ A,
              const float* __restrict__ Wq, const float* __restrict__ Wk,
              const float* __restrict__ Wv,
              const float* __restrict__ bq, const float* __restrict__ bk,
              const float* __restrict__ bv,
              bf16* __restrict__ Qo, bf16* __restrict__ Ka,
              bf16* __restrict__ Va) {
  constexpr int K = 768;
  __shared__ __align__(16) bf16 As[128 * 32];

  const int tid  = threadIdx.x;
  const int wave = tid >> 6;
  const int lane = tid & 63;
  const int l15  = lane & 15;
  const int q4   = lane >> 4;
  const int wr   = wave >> 1;
  const int wc   = wave & 1;
  const int sel  = blockIdx.x / 6;
  const int cb0  = (blockIdx.x % 6) * 128;
  const int rb0  = blockIdx.y * 128;

  const float* W   = (sel == 0) ? Wq : (sel == 1) ? Wk : Wv;
  const float* bia = (sel == 0) ? bq : (sel == 1) ? bk : bv;

  // Per-thread A-DMA source coords (fixed across K-steps).
  const int ar0 = tid >> 2,          akc0 = (tid & 3) << 3;
  const int ar1 = (tid + 256) >> 2,  akc1 = ((tid + 256) & 3) << 3;

  fx4 acc[4][4];
#pragma unroll
  for (int i = 0; i < 4; i++)
#pragma unroll
    for (int j = 0; j < 4; j++) acc[i][j] = (fx4){0.f, 0.f, 0.f, 0.f};

  for (int k0 = 0; k0 < K; k0 += 32) {
    // A -> LDS via DMA (2 instructions, zero dest VGPRs).
    gload_lds16(&A[(size_t)(rb0 + ar0) * K + k0 + akc0], &As[wave * 512]);
    gload_lds16(&A[(size_t)(rb0 + ar1) * K + k0 + akc1], &As[(wave + 4) * 512]);

    // B frags direct from global fp32 (8 contiguous floats per frag).
    float4 bw[4][2];
#pragma unroll
    for (int j = 0; j < 4; j++) {
      const float* wp =
          W + (size_t)(cb0 + wc * 64 + j * 16 + l15) * K + k0 + q4 * 8;
      bw[j][0] = *(const float4*)wp;
      bw[j][1] = *(const float4*)(wp + 4);
    }
    __syncthreads();  // vmcnt(0)+lgkmcnt(0)+barrier: A tile + B regs ready.

    bf16x8 a[4], b[4];
#pragma unroll
    for (int i = 0; i < 4; i++)
      a[i] = *(const bf16x8*)&As[(wr * 64 + i * 16 + l15) * 32 + q4 * 8];
#pragma unroll
    for (int j = 0; j < 4; j++) {
      bf16x8 t;
      t[0] = (bf16)bw[j][0].x; t[1] = (bf16)bw[j][0].y;
      t[2] = (bf16)bw[j][0].z; t[3] = (bf16)bw[j][0].w;
      t[4] = (bf16)bw[j][1].x; t[5] = (bf16)bw[j][1].y;
      t[6] = (bf16)bw[j][1].z; t[7] = (bf16)bw[j][1].w;
      b[j] = t;
    }
#pragma unroll
    for (int i = 0; i < 4; i++)
#pragma unroll
      for (int j = 0; j < 4; j++)
        acc[i][j] = MFMA16(a[i], b[j], acc[i][j]);
    __syncthreads();  // protect As before next DMA overwrites it.
  }

  const int cb = cb0 + wc * 64;
  const int rb = rb0 + wr * 64;
#pragma unroll
  for (int j = 0; j < 4; j++) {
    const int o  = cb + j * 16 + l15;
    const float bj = bia[o];
    const int hh = o / 96;
    const int dd = o - hh * 96;
#pragma unroll
    for (int i = 0; i < 4; i++) {
      const int r0 = rb + i * 16 + q4 * 4;
      if (sel == 2) {
        // V tile: flat = tile*3072 + (k/8)*768 + d*8 + k%8 ; 4 consecutive k
        const int bb = r0 >> 11;
        const int n2 = r0 & 2047;
        const size_t flat =
            ((size_t)((bb * 8 + hh) * 64 + (n2 >> 5))) * 3072 +
            ((n2 >> 3) & 3) * 768 + dd * 8 + (n2 & 7);
        bf16x4 pk;
#pragma unroll
        for (int r = 0; r < 4; r++) pk[r] = (bf16)(acc[i][j][r] + bj);
        *(bf16x4*)&Va[flat] = pk;
      } else if (sel == 1) {
        // K tile: flat = tile*3072 + (d/8)*256 + k*8 + d%8
        const int u  = dd >> 3;
        const int de = dd & 7;
#pragma unroll
        for (int r = 0; r < 4; r++) {
          const int n  = r0 + r;
          const int bb = n >> 11;
          const int n2 = n & 2047;
          const size_t flat =
              ((size_t)((bb * 8 + hh) * 64 + (n2 >> 5))) * 3072 +
              u * 256 + (n2 & 31) * 8 + de;
          Ka[flat] = (bf16)(acc[i][j][r] + bj);
        }
      } else {
#pragma unroll
        for (int r = 0; r < 4; r++)
          Qo[(size_t)(r0 + r) * 768 + o] = (bf16)(acc[i][j][r] + bj);
      }
    }
  }
}

// ---------------------------------------------------------------------------
// Output projection: out[M,768] fp32 = AO bf16 @ Wo^T + bo.
// Same R16 staging: A via DMA, B direct-from-global fp32.
// ---------------------------------------------------------------------------
__global__ __launch_bounds__(256)
void gemm_o(const bf16* __restrict__ A, const float* __restrict__ W,
            const float* __restrict__ bias, float* __restrict__ C) {
  constexpr int K = 768;
  __shared__ __align__(16) bf16 As[128 * 32];

  const int tid  = threadIdx.x;
  const int wave = tid >> 6;
  const int lane = tid & 63;
  const int l15  = lane & 15;
  const int q4   = lane >> 4;
  const int wr   = wave >> 1;
  const int wc   = wave & 1;
  const int rb0  = blockIdx.y * 128;
  const int cb0  = blockIdx.x * 128;

  const int ar0 = tid >> 2,          akc0 = (tid & 3) << 3;
  const int ar1 = (tid + 256) >> 2,  akc1 = ((tid + 256) & 3) << 3;

  fx4 acc[4][4];
#pragma unroll
  for (int i = 0; i < 4; i++)
#pragma unroll
    for (int j = 0; j < 4; j++) acc[i][j] = (fx4){0.f, 0.f, 0.f, 0.f};

  for (int k0 = 0; k0 < K; k0 += 32) {
    gload_lds16(&A[(size_t)(rb0 + ar0) * K + k0 + akc0], &As[wave * 512]);
    gload_lds16(&A[(size_t)(rb0 + ar1) * K + k0 + akc1], &As[(wave + 4) * 512]);

    float4 bw[4][2];
#pragma unroll
    for (int j = 0; j < 4; j++) {
      const float* wp =
          W + (size_t)(cb0 + wc * 64 + j * 16 + l15) * K + k0 + q4 * 8;
      bw[j][0] = *(const float4*)wp;
      bw[j][1] = *(const float4*)(wp + 4);
    }
    __syncthreads();

    bf16x8 a[4], b[4];
#pragma unroll
    for (int i = 0; i < 4; i++)
      a[i] = *(const bf16x8*)&As[(wr * 64 + i * 16 + l15) * 32 + q4 * 8];
#pragma unroll
    for (int j = 0; j < 4; j++) {
      bf16x8 t;
      t[0] = (bf16)bw[j][0].x; t[1] = (bf16)bw[j][0].y;
      t[2] = (bf16)bw[j][0].z; t[3] = (bf16)bw[j][0].w;
      t[4] = (bf16)bw[j][1].x; t[5] = (bf16)bw[j][1].y;
      t[6] = (bf16)bw[j][1].z; t[7] = (bf16)bw[j][1].w;
      b[j] = t;
    }
#pragma unroll
    for (int i = 0; i < 4; i++)
#pragma unroll
      for (int j = 0; j < 4; j++)
        acc[i][j] = MFMA16(a[i], b[j], acc[i][j]);
    __syncthreads();
  }

  const int cb = cb0 + wc * 64;
  const int rb = rb0 + wr * 64;
#pragma unroll
  for (int j = 0; j < 4; j++) {
    const int o  = cb + j * 16 + l15;
    const float bj = bias[o];
#pragma unroll
    for (int i = 0; i < 4; i++) {
      const int r0 = rb + i * 16 + q4 * 4;
#pragma unroll
      for (int r = 0; r < 4; r++)
        C[(size_t)(r0 + r) * 768 + o] = acc[i][j][r] + bj;
    }
  }
}

// ---------------------------------------------------------------------------
// Attention, softmax over HEADS (dim=1), / sqrt(768). R15 version, UNTOUCHED
// (proven 205 -> 141.5 µs): K/V staged via global_load_lds DMA into
// wave-private LDS regions; counted vmcnt(6) waits; nodrain barriers;
// in-place f32 softmax in Ebuf.
// LDS: Kbuf 48 + Vbuf 48 + Ebuf 32.5 = 131.5 KB (1 block/CU by LDS).
// ---------------------------------------------------------------------------
__global__ __launch_bounds__(512, 1)
void attn_kernel(const bf16* Q, const bf16* __restrict__ Ka,
                 const bf16* __restrict__ Va, bf16* AO) {
  __shared__ __align__(16) bf16  Kbuf[8 * 3072];   // [h][u12][k32][8] 48 KB
  __shared__ __align__(16) bf16  Vbuf[8 * 3072];   // [h][ku4][d96][8] 48 KB
  __shared__ __align__(16) float Ebuf[32 * 260];   // [q][h*32+k]    32.5 KB

  const int tid  = threadIdx.x;
  const int h    = tid >> 6;
  const int lane = tid & 63;
  const int l15  = lane & 15;
  const int q4   = lane >> 4;
  const int b    = blockIdx.x >> 6;
  const int qt   = blockIdx.x & 63;
  const int qrow0 = b * 2048 + qt * 32;

  // Persistent Q fragments: 2 q-16tiles x 3 d-chunks.
  bf16x8 aq[2][3];
#pragma unroll
  for (int i = 0; i < 2; i++)
#pragma unroll
    for (int c = 0; c < 3; c++)
      aq[i][c] = *(const bf16x8*)
          &Q[(size_t)(qrow0 + i * 16 + l15) * 768 + h * 96 + c * 32 + q4 * 8];

  fx4 o[2][6];
#pragma unroll
  for (int i = 0; i < 2; i++)
#pragma unroll
    for (int j = 0; j < 6; j++) o[i][j] = (fx4){0.f, 0.f, 0.f, 0.f};

  // Per-head global tile bases (tiles of 3072 elems = 6144 B, [b][h][kt]).
  const bf16* Kt0 = Ka + (size_t)(b * 8 + h) * 64 * 3072;
  const bf16* Vt0 = Va + (size_t)(b * 8 + h) * 64 * 3072;
  bf16* Kl = &Kbuf[h * 3072];
  bf16* Vl = &Vbuf[h * 3072];

  auto stageK = [&](int kt) {
    const bf16* src = Kt0 + (size_t)kt * 3072 + lane * 8;
#pragma unroll
    for (int t = 0; t < 6; t++)
      gload_lds16(src + t * 512, Kl + t * 512);
  };
  auto stageV = [&](int kt) {
    const bf16* src = Vt0 + (size_t)kt * 3072 + lane * 8;
#pragma unroll
    for (int t = 0; t < 6; t++)
      gload_lds16(src + t * 512, Vl + t * 512);
  };

  stageK(0);
  stageV(0);

  for (int kt = 0; kt < 64; kt++) {
    const int kn = (kt + 1 < 64) ? kt + 1 : 63;

    // --- K(kt) ready? (allow V(kt)'s 6 loads outstanding) ---
    wait_vm6();

    // K frags: lane(l15,q4): k=j*16+l15, d-unit=(c*4+q4) -> 16 B, 2-way.
    bf16x8 bk[2][3];
#pragma unroll
    for (int j = 0; j < 2; j++)
#pragma unroll
      for (int c = 0; c < 3; c++)
        bk[j][c] =
            *(const bf16x8*)&Kl[(c * 4 + q4) * 256 + (j * 16 + l15) * 8];

    // K region free once reads retire; DMA next K tile.
    wait_lgkm0();
    stageK(kn);

    // E = Q K^T : [32q x 32k] for this head.
    fx4 e[2][2];
    e[0][0] = e[0][1] = e[1][0] = e[1][1] = (fx4){0.f, 0.f, 0.f, 0.f};
#pragma unroll
    for (int c = 0; c < 3; c++)
#pragma unroll
      for (int j = 0; j < 2; j++) {
        e[0][j] = MFMA16(aq[0][c], bk[j][c], e[0][j]);
        e[1][j] = MFMA16(aq[1][c], bk[j][c], e[1][j]);
      }

    // Scatter E -> Ebuf[q*260 + h*32 + k]
#pragma unroll
    for (int i = 0; i < 2; i++)
#pragma unroll
      for (int j = 0; j < 2; j++)
#pragma unroll
        for (int r = 0; r < 4; r++)
          Ebuf[(i * 16 + q4 * 4 + r) * 260 + h * 32 + j * 16 + l15] =
              e[i][j][r];
    barrier_nodrain();

    // Softmax over heads, IN PLACE (f32). 1024 (q,k) pairs, 2 per thread.
#pragma unroll
    for (int pp = 0; pp < 2; pp++) {
      const int p = tid + pp * 512;
      const int q = p >> 5, k = p & 31;
      float* row = &Ebuf[q * 260 + k];
      float v[8];
#pragma unroll
      for (int hh = 0; hh < 8; hh++) v[hh] = row[hh * 32];
      float m = v[0];
#pragma unroll
      for (int hh = 1; hh < 8; hh++) m = fmaxf(m, v[hh]);
      float sm = 0.f;
#pragma unroll
      for (int hh = 0; hh < 8; hh++) { v[hh] = __expf(v[hh] - m); sm += v[hh]; }
      const float inv = 1.0f / (sm * 27.712812921102035f);  // / sqrt(768)
#pragma unroll
      for (int hh = 0; hh < 8; hh++) row[hh * 32] = v[hh] * inv;
    }
    barrier_nodrain();

    // --- V(kt) ready? (allow K(kn)'s 6 loads outstanding) ---
    wait_vm6();

    // V frags: lane(l15,q4): d=j2*16+l15, k-unit=q4 -> 16 B, 2-way.
    bf16x8 bv[6];
#pragma unroll
    for (int j2 = 0; j2 < 6; j2++)
      bv[j2] = *(const bf16x8*)&Vl[q4 * 768 + (j2 * 16 + l15) * 8];

    // P frags from Ebuf f32 -> bf16.
    bf16x8 ap[2];
#pragma unroll
    for (int i = 0; i < 2; i++) {
      const float* ps = &Ebuf[(i * 16 + l15) * 260 + h * 32 + q4 * 8];
      fx4 p0 = *(const fx4*)ps;
      fx4 p1 = *(const fx4*)(ps + 4);
      bf16x8 t;
      t[0] = (bf16)p0[0]; t[1] = (bf16)p0[1];
      t[2] = (bf16)p0[2]; t[3] = (bf16)p0[3];
      t[4] = (bf16)p1[0]; t[5] = (bf16)p1[1];
      t[6] = (bf16)p1[2]; t[7] = (bf16)p1[3];
      ap[i] = t;
    }

    // V region free; DMA next V tile.
    wait_lgkm0();
    stageV(kn);

    // O += P @ V.
#pragma unroll
    for (int j2 = 0; j2 < 6; j2++) {
      o[0][j2] = MFMA16(ap[0], bv[j2], o[0][j2]);
      o[1][j2] = MFMA16(ap[1], bv[j2], o[1][j2]);
    }
  }

  // Drain outstanding DMA before exit/stores.
  __builtin_amdgcn_s_waitcnt(0x0070);

  // Write AO[qrow0 + q][h*96 + d]
#pragma unroll
  for (int i = 0; i < 2; i++)
#pragma unroll
    for (int j2 = 0; j2 < 6; j2++)
#pragma unroll
      for (int r = 0; r < 4; r++)
        AO[(size_t)(qrow0 + i * 16 + q4 * 4 + r) * 768 + h * 96 + j2 * 16 + l15] =
            (bf16)(o[i][j2][r]);
}

// ---------------------------------------------------------------------------
// Memory plan: d_out = xb + Ka (both dead before gemm_o overwrites d_out).
// ws = Q + Va (25.2 MB). AO aliases Q.
// ---------------------------------------------------------------------------
extern "C" void kernel_launch(void* const* d_in, const int* in_sizes, int n_in,
                              void* d_out, int out_size, void* d_ws,
                              size_t ws_size, hipStream_t stream) {
  const float* x  = (const float*)d_in[0];
  const float* Wq = (const float*)d_in[1];
  const float* bq = (const float*)d_in[2];
  const float* Wk = (const float*)d_in[3];
  const float* bk = (const float*)d_in[4];
  const float* Wv = (const float*)d_in[5];
  const float* bv = (const float*)d_in[6];
  const float* Wo = (const float*)d_in[7];
  const float* bo = (const float*)d_in[8];

  const size_t MN = (size_t)8192 * 768;
  bf16* xb = (bf16*)d_out;
  bf16* Ka = xb + MN;
  bf16* Q  = (bf16*)d_ws;
  bf16* Va = Q + MN;
  bf16* AO = Q;  // aliases Q

  cvt_x_kernel<<<6144, 256, 0, stream>>>(x, xb);
  dim3 qkvgrid(18, 64);
  gemm_qkv<<<qkvgrid, 256, 0, stream>>>(xb, Wq, Wk, Wv, bq, bk, bv, Q, Ka, Va);
  attn_kernel<<<256, 512, 0, stream>>>(Q, Ka, Va, AO);
  dim3 ogrid(6, 64);
  gemm_o<<<ogrid, 256, 0, stream>>>(AO, Wo, bo, (float*)d_out);
}

// Round 7
// 316.435 us; speedup vs baseline: 1.2523x; 1.2523x over previous
//
#include <hip/hip_runtime.h>
#include <stdint.h>

typedef __bf16 bf16;
typedef __bf16 bf16x4 __attribute__((ext_vector_type(4)));
typedef __bf16 bf16x8 __attribute__((ext_vector_type(8)));
typedef float  fx4    __attribute__((ext_vector_type(4)));

#define MFMA16(a, b, c) __builtin_amdgcn_mfma_f32_16x16x32_bf16((a), (b), (c), 0, 0, 0)

// B=4, N=2048, E=768, H=8, D=96; M = B*N = 8192. User tensors fp32, out fp32.

// ---------------------------------------------------------------------------
// Barrier WITHOUT the vmem drain (lgkmcnt(0) only). Keeps global_load_lds
// DMA in flight across barriers. 0xC07F = vmcnt 63 (nowait), exp 7, lgkm 0.
// ---------------------------------------------------------------------------
__device__ __forceinline__ void barrier_nodrain() {
  __asm__ __volatile__("" ::: "memory");
  __builtin_amdgcn_s_waitcnt(0xC07F);
  __builtin_amdgcn_s_barrier();
  __asm__ __volatile__("" ::: "memory");
}

// Counted vmem wait: vmcnt(6) — wait oldest loads, allow 6 newest in flight.
__device__ __forceinline__ void wait_vm6() {
  __asm__ __volatile__("" ::: "memory");
  __builtin_amdgcn_s_waitcnt(0x0F76);
  __asm__ __volatile__("" ::: "memory");
}
// lgkmcnt(0) only (LDS reads retired; region safe to overwrite).
__device__ __forceinline__ void wait_lgkm0() {
  __asm__ __volatile__("" ::: "memory");
  __builtin_amdgcn_s_waitcnt(0xC07F);
  __asm__ __volatile__("" ::: "memory");
}

// DMA 16 B/lane global -> LDS (dest = wave-uniform base + lane*16, m104).
__device__ __forceinline__ void gload_lds16(const void* g, void* l) {
  __builtin_amdgcn_global_load_lds(
      (const __attribute__((address_space(1))) void*)g,
      (__attribute__((address_space(3))) void*)l, 16, 0, 0);
}

// ---------------------------------------------------------------------------
// x (fp32) -> bf16, 4 elems/thread.
// ---------------------------------------------------------------------------
__global__ __launch_bounds__(256)
void cvt_x_kernel(const float* __restrict__ x, bf16* __restrict__ xb) {
  const int i = (blockIdx.x * 256 + threadIdx.x) * 4;
  float4 v = *(const float4*)&x[i];
  bf16x4 o;
  o[0] = (bf16)v.x; o[1] = (bf16)v.y; o[2] = (bf16)v.z; o[3] = (bf16)v.w;
  *(bf16x4*)&xb[i] = o;
}

// ---------------------------------------------------------------------------
// Fused QKV GEMM. blockIdx.x: 0-5 Q, 6-11 K, 12-17 V. Tile 128x128, BK=32.
// R17: R16 post-mortem — per-wave B gather (32 B/lane @ 3072 B stride) was
// a 16-line uncoalesced load and regressed 75 µs. Revert B to R15's
// COALESCED cooperative staging (fp32 float4 + cvt + ds_write). Keep A via
// global_load_lds DMA (mapping harness-proven in R16), now DOUBLE-BUFFERED:
// DMA A(k+1) issues before B's cvt; cvt's implicit waitcnt drains B + old
// A(k) but leaves A(k+1) in flight (FIFO vmcnt); nodrain barriers never
// flush it. Cross-wave: own-wave cvt-wait retires own A(k) before barrier.
// LDS 24 KB -> ~6 blocks/CU.
// K/V outputs in attention-staging tile layout (R15/R16, harness-proven):
//   K: [b][h][kt][u=d/8][k32][d%8]   V: [b][h][kt][ku=k/8][d96][k%8]
// ---------------------------------------------------------------------------
__global__ __launch_bounds__(256)
void gemm_qkv(const bf16* __restrict__ A,
              const float* __restrict__ Wq, const float* __restrict__ Wk,
              const float* __restrict__ Wv,
              const float* __restrict__ bq, const float* __restrict__ bk,
              const float* __restrict__ bv,
              bf16* __restrict__ Qo, bf16* __restrict__ Ka,
              bf16* __restrict__ Va) {
  constexpr int K = 768;
  __shared__ __align__(16) bf16 As[2][128 * 32];  // 2 x 8 KB (DMA dbuf)
  __shared__ __align__(16) bf16 Bs[128 * 32];     // 8 KB

  const int tid  = threadIdx.x;
  const int wave = tid >> 6;
  const int lane = tid & 63;
  const int l15  = lane & 15;
  const int q4   = lane >> 4;
  const int wr   = wave >> 1;
  const int wc   = wave & 1;
  const int sel  = blockIdx.x / 6;
  const int cb0  = (blockIdx.x % 6) * 128;
  const int rb0  = blockIdx.y * 128;

  const float* W   = (sel == 0) ? Wq : (sel == 1) ? Wk : Wv;
  const float* bia = (sel == 0) ? bq : (sel == 1) ? bk : bv;

  // Per-thread staging coords (fixed across K-steps). row=c>>2, kc=(c&3)*8.
  const int ar0 = tid >> 2,         akc0 = (tid & 3) << 3;
  const int ar1 = ar0 + 64,         akc1 = akc0;

  fx4 acc[4][4];
#pragma unroll
  for (int i = 0; i < 4; i++)
#pragma unroll
    for (int j = 0; j < 4; j++) acc[i][j] = (fx4){0.f, 0.f, 0.f, 0.f};

  // Prologue: DMA A(k=0) into As[0].
  gload_lds16(&A[(size_t)(rb0 + ar0) * K + akc0], &As[0][wave * 512]);
  gload_lds16(&A[(size_t)(rb0 + ar1) * K + akc1], &As[0][(wave + 4) * 512]);

  int cur = 0;
  for (int k0 = 0; k0 < K; k0 += 32, cur ^= 1) {
    // B loads: coalesced fp32 (consecutive tids -> consecutive 32 B).
    const float* wp0 = W + (size_t)(cb0 + ar0) * K + k0 + akc0;
    const float* wp1 = W + (size_t)(cb0 + ar1) * K + k0 + akc1;
    const float4 b0a = *(const float4*)wp0;
    const float4 b0b = *(const float4*)(wp0 + 4);
    const float4 b1a = *(const float4*)wp1;
    const float4 b1b = *(const float4*)(wp1 + 4);
    __asm__ __volatile__("" ::: "memory");

    // DMA NEXT A tile into the other buffer (stays in flight across MFMA).
    const int kn = (k0 + 32 < K) ? k0 + 32 : k0;  // last iter: harmless redo
    gload_lds16(&A[(size_t)(rb0 + ar0) * K + kn + akc0],
                &As[cur ^ 1][wave * 512]);
    gload_lds16(&A[(size_t)(rb0 + ar1) * K + kn + akc1],
                &As[cur ^ 1][(wave + 4) * 512]);
    __asm__ __volatile__("" ::: "memory");

    // Convert + stage B (cvt's implicit wait drains B + old A, not A(kn)).
    bf16x8 pb0, pb1;
    pb0[0] = (bf16)b0a.x; pb0[1] = (bf16)b0a.y;
    pb0[2] = (bf16)b0a.z; pb0[3] = (bf16)b0a.w;
    pb0[4] = (bf16)b0b.x; pb0[5] = (bf16)b0b.y;
    pb0[6] = (bf16)b0b.z; pb0[7] = (bf16)b0b.w;
    pb1[0] = (bf16)b1a.x; pb1[1] = (bf16)b1a.y;
    pb1[2] = (bf16)b1a.z; pb1[3] = (bf16)b1a.w;
    pb1[4] = (bf16)b1b.x; pb1[5] = (bf16)b1b.y;
    pb1[6] = (bf16)b1b.z; pb1[7] = (bf16)b1b.w;
    *(bf16x8*)&Bs[ar0 * 32 + akc0] = pb0;
    *(bf16x8*)&Bs[ar1 * 32 + akc1] = pb1;

    barrier_nodrain();  // lgkm0: Bs visible; A(k0) resident (cvt-wait + bar)

    bf16x8 a[4], b[4];
#pragma unroll
    for (int i = 0; i < 4; i++)
      a[i] = *(const bf16x8*)&As[cur][(wr * 64 + i * 16 + l15) * 32 + q4 * 8];
#pragma unroll
    for (int j = 0; j < 4; j++)
      b[j] = *(const bf16x8*)&Bs[(wc * 64 + j * 16 + l15) * 32 + q4 * 8];
#pragma unroll
    for (int i = 0; i < 4; i++)
#pragma unroll
      for (int j = 0; j < 4; j++)
        acc[i][j] = MFMA16(a[i], b[j], acc[i][j]);

    barrier_nodrain();  // own ds_reads retired before Bs/As restage
  }

  const int cb = cb0 + wc * 64;
  const int rb = rb0 + wr * 64;
#pragma unroll
  for (int j = 0; j < 4; j++) {
    const int o  = cb + j * 16 + l15;
    const float bj = bia[o];
    const int hh = o / 96;
    const int dd = o - hh * 96;
#pragma unroll
    for (int i = 0; i < 4; i++) {
      const int r0 = rb + i * 16 + q4 * 4;
      if (sel == 2) {
        // V tile: flat = tile*3072 + (k/8)*768 + d*8 + k%8 ; 4 consecutive k
        const int bb = r0 >> 11;
        const int n2 = r0 & 2047;
        const size_t flat =
            ((size_t)((bb * 8 + hh) * 64 + (n2 >> 5))) * 3072 +
            ((n2 >> 3) & 3) * 768 + dd * 8 + (n2 & 7);
        bf16x4 pk;
#pragma unroll
        for (int r = 0; r < 4; r++) pk[r] = (bf16)(acc[i][j][r] + bj);
        *(bf16x4*)&Va[flat] = pk;
      } else if (sel == 1) {
        // K tile: flat = tile*3072 + (d/8)*256 + k*8 + d%8
        const int u  = dd >> 3;
        const int de = dd & 7;
#pragma unroll
        for (int r = 0; r < 4; r++) {
          const int n  = r0 + r;
          const int bb = n >> 11;
          const int n2 = n & 2047;
          const size_t flat =
              ((size_t)((bb * 8 + hh) * 64 + (n2 >> 5))) * 3072 +
              u * 256 + (n2 & 31) * 8 + de;
          Ka[flat] = (bf16)(acc[i][j][r] + bj);
        }
      } else {
#pragma unroll
        for (int r = 0; r < 4; r++)
          Qo[(size_t)(r0 + r) * 768 + o] = (bf16)(acc[i][j][r] + bj);
      }
    }
  }
}

// ---------------------------------------------------------------------------
// Output projection: out[M,768] fp32 = AO bf16 @ Wo^T + bo.
// Same R17 structure: A DMA double-buffered, B coalesced reg-staged.
// ---------------------------------------------------------------------------
__global__ __launch_bounds__(256)
void gemm_o(const bf16* __restrict__ A, const float* __restrict__ W,
            const float* __restrict__ bias, float* __restrict__ C) {
  constexpr int K = 768;
  __shared__ __align__(16) bf16 As[2][128 * 32];
  __shared__ __align__(16) bf16 Bs[128 * 32];

  const int tid  = threadIdx.x;
  const int wave = tid >> 6;
  const int lane = tid & 63;
  const int l15  = lane & 15;
  const int q4   = lane >> 4;
  const int wr   = wave >> 1;
  const int wc   = wave & 1;
  const int rb0  = blockIdx.y * 128;
  const int cb0  = blockIdx.x * 128;

  const int ar0 = tid >> 2,         akc0 = (tid & 3) << 3;
  const int ar1 = ar0 + 64,         akc1 = akc0;

  fx4 acc[4][4];
#pragma unroll
  for (int i = 0; i < 4; i++)
#pragma unroll
    for (int j = 0; j < 4; j++) acc[i][j] = (fx4){0.f, 0.f, 0.f, 0.f};

  gload_lds16(&A[(size_t)(rb0 + ar0) * K + akc0], &As[0][wave * 512]);
  gload_lds16(&A[(size_t)(rb0 + ar1) * K + akc1], &As[0][(wave + 4) * 512]);

  int cur = 0;
  for (int k0 = 0; k0 < K; k0 += 32, cur ^= 1) {
    const float* wp0 = W + (size_t)(cb0 + ar0) * K + k0 + akc0;
    const float* wp1 = W + (size_t)(cb0 + ar1) * K + k0 + akc1;
    const float4 b0a = *(const float4*)wp0;
    const float4 b0b = *(const float4*)(wp0 + 4);
    const float4 b1a = *(const float4*)wp1;
    const float4 b1b = *(const float4*)(wp1 + 4);
    __asm__ __volatile__("" ::: "memory");

    const int kn = (k0 + 32 < K) ? k0 + 32 : k0;
    gload_lds16(&A[(size_t)(rb0 + ar0) * K + kn + akc0],
                &As[cur ^ 1][wave * 512]);
    gload_lds16(&A[(size_t)(rb0 + ar1) * K + kn + akc1],
                &As[cur ^ 1][(wave + 4) * 512]);
    __asm__ __volatile__("" ::: "memory");

    bf16x8 pb0, pb1;
    pb0[0] = (bf16)b0a.x; pb0[1] = (bf16)b0a.y;
    pb0[2] = (bf16)b0a.z; pb0[3] = (bf16)b0a.w;
    pb0[4] = (bf16)b0b.x; pb0[5] = (bf16)b0b.y;
    pb0[6] = (bf16)b0b.z; pb0[7] = (bf16)b0b.w;
    pb1[0] = (bf16)b1a.x; pb1[1] = (bf16)b1a.y;
    pb1[2] = (bf16)b1a.z; pb1[3] = (bf16)b1a.w;
    pb1[4] = (bf16)b1b.x; pb1[5] = (bf16)b1b.y;
    pb1[6] = (bf16)b1b.z; pb1[7] = (bf16)b1b.w;
    *(bf16x8*)&Bs[ar0 * 32 + akc0] = pb0;
    *(bf16x8*)&Bs[ar1 * 32 + akc1] = pb1;

    barrier_nodrain();

    bf16x8 a[4], b[4];
#pragma unroll
    for (int i = 0; i < 4; i++)
      a[i] = *(const bf16x8*)&As[cur][(wr * 64 + i * 16 + l15) * 32 + q4 * 8];
#pragma unroll
    for (int j = 0; j < 4; j++)
      b[j] = *(const bf16x8*)&Bs[(wc * 64 + j * 16 + l15) * 32 + q4 * 8];
#pragma unroll
    for (int i = 0; i < 4; i++)
#pragma unroll
      for (int j = 0; j < 4; j++)
        acc[i][j] = MFMA16(a[i], b[j], acc[i][j]);

    barrier_nodrain();
  }

  const int cb = cb0 + wc * 64;
  const int rb = rb0 + wr * 64;
#pragma unroll
  for (int j = 0; j < 4; j++) {
    const int o  = cb + j * 16 + l15;
    const float bj = bias[o];
#pragma unroll
    for (int i = 0; i < 4; i++) {
      const int r0 = rb + i * 16 + q4 * 4;
#pragma unroll
      for (int r = 0; r < 4; r++)
        C[(size_t)(r0 + r) * 768 + o] = acc[i][j][r] + bj;
    }
  }
}

// ---------------------------------------------------------------------------
// Attention, softmax over HEADS (dim=1), / sqrt(768). R15 version, UNTOUCHED
// (proven 205 -> 141.5 µs): K/V staged via global_load_lds DMA into
// wave-private LDS regions; counted vmcnt(6) waits; nodrain barriers;
// in-place f32 softmax in Ebuf.
// LDS: Kbuf 48 + Vbuf 48 + Ebuf 32.5 = 131.5 KB (1 block/CU by LDS).
// ---------------------------------------------------------------------------
__global__ __launch_bounds__(512, 1)
void attn_kernel(const bf16* Q, const bf16* __restrict__ Ka,
                 const bf16* __restrict__ Va, bf16* AO) {
  __shared__ __align__(16) bf16  Kbuf[8 * 3072];   // [h][u12][k32][8] 48 KB
  __shared__ __align__(16) bf16  Vbuf[8 * 3072];   // [h][ku4][d96][8] 48 KB
  __shared__ __align__(16) float Ebuf[32 * 260];   // [q][h*32+k]    32.5 KB

  const int tid  = threadIdx.x;
  const int h    = tid >> 6;
  const int lane = tid & 63;
  const int l15  = lane & 15;
  const int q4   = lane >> 4;
  const int b    = blockIdx.x >> 6;
  const int qt   = blockIdx.x & 63;
  const int qrow0 = b * 2048 + qt * 32;

  // Persistent Q fragments: 2 q-16tiles x 3 d-chunks.
  bf16x8 aq[2][3];
#pragma unroll
  for (int i = 0; i < 2; i++)
#pragma unroll
    for (int c = 0; c < 3; c++)
      aq[i][c] = *(const bf16x8*)
          &Q[(size_t)(qrow0 + i * 16 + l15) * 768 + h * 96 + c * 32 + q4 * 8];

  fx4 o[2][6];
#pragma unroll
  for (int i = 0; i < 2; i++)
#pragma unroll
    for (int j = 0; j < 6; j++) o[i][j] = (fx4){0.f, 0.f, 0.f, 0.f};

  // Per-head global tile bases (tiles of 3072 elems = 6144 B, [b][h][kt]).
  const bf16* Kt0 = Ka + (size_t)(b * 8 + h) * 64 * 3072;
  const bf16* Vt0 = Va + (size_t)(b * 8 + h) * 64 * 3072;
  bf16* Kl = &Kbuf[h * 3072];
  bf16* Vl = &Vbuf[h * 3072];

  auto stageK = [&](int kt) {
    const bf16* src = Kt0 + (size_t)kt * 3072 + lane * 8;
#pragma unroll
    for (int t = 0; t < 6; t++)
      gload_lds16(src + t * 512, Kl + t * 512);
  };
  auto stageV = [&](int kt) {
    const bf16* src = Vt0 + (size_t)kt * 3072 + lane * 8;
#pragma unroll
    for (int t = 0; t < 6; t++)
      gload_lds16(src + t * 512, Vl + t * 512);
  };

  stageK(0);
  stageV(0);

  for (int kt = 0; kt < 64; kt++) {
    const int kn = (kt + 1 < 64) ? kt + 1 : 63;

    // --- K(kt) ready? (allow V(kt)'s 6 loads outstanding) ---
    wait_vm6();

    // K frags: lane(l15,q4): k=j*16+l15, d-unit=(c*4+q4) -> 16 B, 2-way.
    bf16x8 bk[2][3];
#pragma unroll
    for (int j = 0; j < 2; j++)
#pragma unroll
      for (int c = 0; c < 3; c++)
        bk[j][c] =
            *(const bf16x8*)&Kl[(c * 4 + q4) * 256 + (j * 16 + l15) * 8];

    // K region free once reads retire; DMA next K tile.
    wait_lgkm0();
    stageK(kn);

    // E = Q K^T : [32q x 32k] for this head.
    fx4 e[2][2];
    e[0][0] = e[0][1] = e[1][0] = e[1][1] = (fx4){0.f, 0.f, 0.f, 0.f};
#pragma unroll
    for (int c = 0; c < 3; c++)
#pragma unroll
      for (int j = 0; j < 2; j++) {
        e[0][j] = MFMA16(aq[0][c], bk[j][c], e[0][j]);
        e[1][j] = MFMA16(aq[1][c], bk[j][c], e[1][j]);
      }

    // Scatter E -> Ebuf[q*260 + h*32 + k]
#pragma unroll
    for (int i = 0; i < 2; i++)
#pragma unroll
      for (int j = 0; j < 2; j++)
#pragma unroll
        for (int r = 0; r < 4; r++)
          Ebuf[(i * 16 + q4 * 4 + r) * 260 + h * 32 + j * 16 + l15] =
              e[i][j][r];
    barrier_nodrain();

    // Softmax over heads, IN PLACE (f32). 1024 (q,k) pairs, 2 per thread.
#pragma unroll
    for (int pp = 0; pp < 2; pp++) {
      const int p = tid + pp * 512;
      const int q = p >> 5, k = p & 31;
      float* row = &Ebuf[q * 260 + k];
      float v[8];
#pragma unroll
      for (int hh = 0; hh < 8; hh++) v[hh] = row[hh * 32];
      float m = v[0];
#pragma unroll
      for (int hh = 1; hh < 8; hh++) m = fmaxf(m, v[hh]);
      float sm = 0.f;
#pragma unroll
      for (int hh = 0; hh < 8; hh++) { v[hh] = __expf(v[hh] - m); sm += v[hh]; }
      const float inv = 1.0f / (sm * 27.712812921102035f);  // / sqrt(768)
#pragma unroll
      for (int hh = 0; hh < 8; hh++) row[hh * 32] = v[hh] * inv;
    }
    barrier_nodrain();

    // --- V(kt) ready? (allow K(kn)'s 6 loads outstanding) ---
    wait_vm6();

    // V frags: lane(l15,q4): d=j2*16+l15, k-unit=q4 -> 16 B, 2-way.
    bf16x8 bv[6];
#pragma unroll
    for (int j2 = 0; j2 < 6; j2++)
      bv[j2] = *(const bf16x8*)&Vl[q4 * 768 + (j2 * 16 + l15) * 8];

    // P frags from Ebuf f32 -> bf16.
    bf16x8 ap[2];
#pragma unroll
    for (int i = 0; i < 2; i++) {
      const float* ps = &Ebuf[(i * 16 + l15) * 260 + h * 32 + q4 * 8];
      fx4 p0 = *(const fx4*)ps;
      fx4 p1 = *(const fx4*)(ps + 4);
      bf16x8 t;
      t[0] = (bf16)p0[0]; t[1] = (bf16)p0[1];
      t[2] = (bf16)p0[2]; t[3] = (bf16)p0[3];
      t[4] = (bf16)p1[0]; t[5] = (bf16)p1[1];
      t[6] = (bf16)p1[2]; t[7] = (bf16)p1[3];
      ap[i] = t;
    }

    // V region free; DMA next V tile.
    wait_lgkm0();
    stageV(kn);

    // O += P @ V.
#pragma unroll
    for (int j2 = 0; j2 < 6; j2++) {
      o[0][j2] = MFMA16(ap[0], bv[j2], o[0][j2]);
      o[1][j2] = MFMA16(ap[1], bv[j2], o[1][j2]);
    }
  }

  // Drain outstanding DMA before exit/stores.
  __builtin_amdgcn_s_waitcnt(0x0070);

  // Write AO[qrow0 + q][h*96 + d]
#pragma unroll
  for (int i = 0; i < 2; i++)
#pragma unroll
    for (int j2 = 0; j2 < 6; j2++)
#pragma unroll
      for (int r = 0; r < 4; r++)
        AO[(size_t)(qrow0 + i * 16 + q4 * 4 + r) * 768 + h * 96 + j2 * 16 + l15] =
            (bf16)(o[i][j2][r]);
}

// ---------------------------------------------------------------------------
// Memory plan: d_out = xb + Ka (both dead before gemm_o overwrites d_out).
// ws = Q + Va (25.2 MB). AO aliases Q.
// ---------------------------------------------------------------------------
extern "C" void kernel_launch(void* const* d_in, const int* in_sizes, int n_in,
                              void* d_out, int out_size, void* d_ws,
                              size_t ws_size, hipStream_t stream) {
  const float* x  = (const float*)d_in[0];
  const float* Wq = (const float*)d_in[1];
  const float* bq = (const float*)d_in[2];
  const float* Wk = (const float*)d_in[3];
  const float* bk = (const float*)d_in[4];
  const float* Wv = (const float*)d_in[5];
  const float* bv = (const float*)d_in[6];
  const float* Wo = (const float*)d_in[7];
  const float* bo = (const float*)d_in[8];

  const size_t MN = (size_t)8192 * 768;
  bf16* xb = (bf16*)d_out;
  bf16* Ka = xb + MN;
  bf16* Q  = (bf16*)d_ws;
  bf16* Va = Q + MN;
  bf16* AO = Q;  // aliases Q

  cvt_x_kernel<<<6144, 256, 0, stream>>>(x, xb);
  dim3 qkvgrid(18, 64);
  gemm_qkv<<<qkvgrid, 256, 0, stream>>>(xb, Wq, Wk, Wv, bq, bk, bv, Q, Ka, Va);
  attn_kernel<<<256, 512, 0, stream>>>(Q, Ka, Va, AO);
  dim3 ogrid(6, 64);
  gemm_o<<<ogrid, 256, 0, stream>>>(AO, Wo, bo, (float*)d_out);
}